// Round 17
// baseline (112.076 us; speedup 1.0000x reference)
//
#include <hip/hip_runtime.h>

#define AS_GLOBAL __attribute__((address_space(1)))
#define AS_LDS    __attribute__((address_space(3)))

typedef __bf16 bf16;
typedef __bf16 bf16x4 __attribute__((ext_vector_type(4)));
typedef __bf16 bf16x8 __attribute__((ext_vector_type(8)));
typedef float  f32x4  __attribute__((ext_vector_type(4)));
typedef unsigned short u16x8 __attribute__((ext_vector_type(8)));

__device__ __forceinline__ void gload16(const void* g, void* l) {
  __builtin_amdgcn_global_load_lds((const AS_GLOBAL unsigned int*)g,
                                   (AS_LDS unsigned int*)l, 16, 0, 0);
}

// swizzled LDS address for a [R][128B] row-major tile:
// stored_byte = row*128 + (bytecol ^ ((row&7)<<4))
__device__ __forceinline__ void* swz(void* base, int row, int bytecol) {
  return (char*)base + row * 128 + (bytecol ^ ((row & 7) << 4));
}

// compacted-column helpers: kept columns are s with !(s%3==1 && s>=4).
__device__ __forceinline__ int keptcnt(int X) { return X - ((X - 2) < 0 ? 0 : (X - 2) / 3); }
__device__ __forceinline__ int ci2s(int ci) {
  return 3 * ((ci - 2) >> 1) + 2 + ((ci - 2) & 1);
}
__device__ __forceinline__ int ci2s_full(int ci) {
  return ci < 2 ? ci : ci2s(ci);
}

// ---------------- fused prep: x->bf16 | 4x W^T | bias concat --------------
__global__ __launch_bounds__(256) void k_prep(const float* __restrict__ x,
                                              const float* __restrict__ Wq,
                                              const float* __restrict__ Wk,
                                              const float* __restrict__ Wv,
                                              const float* __restrict__ Wp,
                                              const float* __restrict__ bq,
                                              const float* __restrict__ bk,
                                              const float* __restrict__ bv,
                                              bf16* __restrict__ xb,
                                              bf16* __restrict__ wqkvT,
                                              bf16* __restrict__ wpT,
                                              float* __restrict__ bc) {
  int blk = blockIdx.x;
  if (blk < 2048) {
    int i = blk * 256 + threadIdx.x;
    const float4* p = (const float4*)(x + (size_t)i * 8);
    float4 a = p[0], b = p[1];
    bf16x8 v;
    v[0] = (bf16)a.x; v[1] = (bf16)a.y; v[2] = (bf16)a.z; v[3] = (bf16)a.w;
    v[4] = (bf16)b.x; v[5] = (bf16)b.y; v[6] = (bf16)b.z; v[7] = (bf16)b.w;
    *(bf16x8*)(xb + (size_t)i * 8) = v;
  } else if (blk < 4096) {
    int wblk = blk - 2048;
    int sel = wblk >> 9;
    const float* W = (sel == 0) ? Wq : (sel == 1) ? Wk : (sel == 2) ? Wv : Wp;
    bf16* dst = (sel < 3) ? (wqkvT + (size_t)sel * 1024 * 1024) : wpT;
    int lin = (wblk & 511) * 256 + threadIdx.x;
    int n = lin & 1023, kc = lin >> 10;
    bf16x8 v;
#pragma unroll
    for (int j = 0; j < 8; ++j) v[j] = (bf16)W[(size_t)(kc * 8 + j) * 1024 + n];
    *(bf16x8*)&dst[(size_t)n * 1024 + kc * 8] = v;
  } else {
    int i = (blk - 4096) * 256 + threadIdx.x;   // 0..3071
    bc[i] = (i < 1024) ? bq[i] : (i < 2048 ? bk[i - 1024] : bv[i - 2048]);
  }
}

// ---------------- V compact: gather + transpose -> Vc[bh][64][1408] -------
__global__ __launch_bounds__(256) void k_compact(const bf16* __restrict__ qkv,
                                                 bf16* __restrict__ vc) {
  __shared__ unsigned L[32 * 65];
  int blk = blockIdx.x;                 // 32 bh * 22 cichunks = 704
  int tid = threadIdx.x;
  int bh = blk / 22, cc = blk % 22;
  int b = bh >> 4, h = bh & 15;
  int ci0 = cc * 64;
  int p = tid >> 3, d0 = (tid & 7) * 8;
  int s0 = ci2s_full(ci0 + 2 * p), s1 = ci2s_full(ci0 + 2 * p + 1);
  u16x8 e = {}, od = {};
  if (s0 < 2048)
    e = *(const u16x8*)&qkv[(size_t)(b * 2048 + s0) * 3072 + 2048 + h * 64 + d0];
  if (s1 < 2048)
    od = *(const u16x8*)&qkv[(size_t)(b * 2048 + s1) * 3072 + 2048 + h * 64 + d0];
#pragma unroll
  for (int k2 = 0; k2 < 8; ++k2)
    L[p * 65 + d0 + k2] = (unsigned)e[k2] | ((unsigned)od[k2] << 16);
  __syncthreads();
#pragma unroll
  for (int it = 0; it < 2; ++it) {
    int d = it * 32 + (tid >> 3), jg = tid & 7;
    unsigned q4[4];
#pragma unroll
    for (int jj = 0; jj < 4; ++jj) q4[jj] = L[(jg * 4 + jj) * 65 + d];
    *(uint4*)&vc[((size_t)bh * 64 + d) * 1408 + ci0 + jg * 8] = *(uint4*)q4;
  }
}

// ---------------- dbuf GEMM, templated tile TMxTN, BK ---------------------
template <typename OutT, int TM, int TN, int BK>
__global__ __launch_bounds__(256) void k_gemm_bt(const bf16* __restrict__ A,
                                                 const bf16* __restrict__ Bt,
                                                 const float* __restrict__ bias,
                                                 OutT* __restrict__ C,
                                                 int K, int N) {
  constexpr int GR = BK / 8;            // 16B granules per LDS row
  constexpr int MF = TM / 32, NF = TN / 32, KF = BK / 32;
  __shared__ bf16 As[2][TM * BK];
  __shared__ bf16 Bs[2][TN * BK];
  const int tid = threadIdx.x;
  const int w = tid >> 6, l = tid & 63, g = l >> 4, c = l & 15;
  const int wr = w >> 1, wc = w & 1;
  int lin = blockIdx.y * gridDim.x + blockIdx.x;
  int chunk = (gridDim.x * gridDim.y) >> 3;
  int nl = (lin & 7) * chunk + (lin >> 3);
  const int row0 = (nl % gridDim.x) * TM, col0 = (nl / gridDim.x) * TN;
  f32x4 acc[MF][NF] = {};

  auto swzj = [&](int j, int r) {
    if constexpr (BK == 32) return j ^ ((r >> 1) & 3);
    else                    return j ^ (r & 7);
  };

  auto stage = [&](int buf, int k0) {
#pragma unroll
    for (int it = 0; it < (TM * GR) / 256; ++it) {
      int idx = it * 256 + tid;
      int r = idx / GR, j = idx % GR;
      gload16(A + (size_t)(row0 + r) * K + k0 + swzj(j, r) * 8, &As[buf][idx * 8]);
    }
#pragma unroll
    for (int it = 0; it < (TN * GR) / 256; ++it) {
      int idx = it * 256 + tid;
      int r = idx / GR, j = idx % GR;
      gload16(Bt + (size_t)(col0 + r) * K + k0 + swzj(j, r) * 8, &Bs[buf][idx * 8]);
    }
  };

  stage(0, 0);
  int cur = 0;
#pragma unroll 1
  for (int k0 = 0; k0 < K; k0 += BK) {
    __syncthreads();   // drains vmcnt (stage(k0) landed) + full memory fence

    if (k0 + BK < K) stage(cur ^ 1, k0 + BK);

    bf16x8 af[MF][KF], bfr[NF][KF];
#pragma unroll
    for (int m = 0; m < MF; ++m) {
      int row = wr * (TM / 2) + m * 16 + c;
#pragma unroll
      for (int kk = 0; kk < KF; ++kk)
        af[m][kk] = *(const bf16x8*)&As[cur][row * BK + swzj(kk * 4 + g, row) * 8];
    }
#pragma unroll
    for (int n = 0; n < NF; ++n) {
      int row = wc * (TN / 2) + n * 16 + c;
#pragma unroll
      for (int kk = 0; kk < KF; ++kk)
        bfr[n][kk] = *(const bf16x8*)&Bs[cur][row * BK + swzj(kk * 4 + g, row) * 8];
    }
#pragma unroll
    for (int m = 0; m < MF; ++m)
#pragma unroll
      for (int n = 0; n < NF; ++n)
#pragma unroll
        for (int kk = 0; kk < KF; ++kk)
          acc[m][n] = __builtin_amdgcn_mfma_f32_16x16x32_bf16(af[m][kk], bfr[n][kk],
                                                              acc[m][n], 0, 0, 0);
    cur ^= 1;
  }

#pragma unroll
  for (int m = 0; m < MF; ++m) {
    int row = row0 + wr * (TM / 2) + m * 16 + g * 4;
#pragma unroll
    for (int n = 0; n < NF; ++n) {
      int col = col0 + wc * (TN / 2) + n * 16 + c;
      float bv = bias[col];
#pragma unroll
      for (int r = 0; r < 4; ++r) {
        float v = acc[m][n][r] + bv;
        C[(size_t)(row + r) * N + col] = (OutT)v;
      }
    }
  }
}

// ---------------- flash attention v13: chain-split (flash-decoding) -------
// 1536 blocks: per bh (32), j2 = idx>>5 in [0,48):
//   j2 < 16: qt = j2, full s-range, writes att directly (chains <= 11 tiles).
//   j2 >= 16: qt = 16 + (j2-16)/2, half = (j2-16)&1 -> half the s-tile range
//     (chains <= 11), emits (o, m, l) partials; k_merge combines.
// Rationale: attn wall == longest serial chain (qt=31: 22 tiles). Split
// halves it; all chains now <= ~12 tiles. half0 never touches the causal
// boundary (nth <= tmaskw always) -> pure clean-tile path.
__global__ __launch_bounds__(256, 4) void k_attn(const bf16* __restrict__ qkv,
                                                 const bf16* __restrict__ vc,
                                                 bf16* __restrict__ att,
                                                 float* __restrict__ po,
                                                 float* __restrict__ pml) {
  const int idx = blockIdx.x;               // 1536; idx%8 == bh%8 (XCD)
  const int bh = idx & 31, j2 = idx >> 5;
  const int b = bh >> 4, h = bh & 15;
  int qt, half = 0;
  const bool split = (j2 >= 16);
  if (!split) { qt = j2; }
  else { int k = j2 - 16; qt = 16 + (k >> 1); half = k & 1; }

  const int tid = threadIdx.x;
  const int w = tid >> 6, l = tid & 63, g = l >> 4, c = l & 15;
  const int qw0 = qt * 64 + w * 16;
  const int qq = qw0 + c;

  const int nt = (keptcnt(qt * 64 + 64) + 63) >> 6;
  const int tmaskw = keptcnt(qw0 + 1) >> 6;
  int t0 = 0, t1 = nt, slot = 0;
  if (split) {
    int nth = nt >> 1;
    if (half) t0 = nth; else t1 = nth;
    slot = (bh * 16 + (qt - 16)) * 2 + half;
  }

  __shared__ bf16 Ks[2][64 * 64];
  __shared__ bf16 Vs[2][64 * 64];
  __shared__ bf16 Plds[4][16 * 64];

  const bf16* vgc = vc + (size_t)bh * 64 * 1408;

  auto stage = [&](int buf, int t) {
    int s0 = t * 64;
#pragma unroll
    for (int it = 0; it < 2; ++it) {
      int ch = it * 256 + tid;
      int rr = ch >> 3, jj = (ch & 7) ^ (rr & 7);
      int s = ci2s_full(s0 + rr);
      s = (s < 2048) ? s : 0;             // pad: load row 0; masked by s<=qq
      gload16(qkv + (size_t)(b * 2048 + s) * 3072 + 1024 + h * 64 + jj * 8,
              &Ks[buf][ch * 8]);
      gload16(vgc + (size_t)rr * 1408 + s0 + jj * 8, &Vs[buf][ch * 8]);
    }
  };

  // Q B-frag, pre-scaled by 0.125*log2e -> S in log2 domain
  const float QSCL = 0.125f * 1.44269504f;
  const bf16* qb = qkv + (size_t)(b * 2048 + qq) * 3072 + h * 64 + g * 8;
  bf16x8 qf0 = *(const bf16x8*)qb;
  bf16x8 qf1 = *(const bf16x8*)(qb + 32);
#pragma unroll
  for (int jq = 0; jq < 8; ++jq) {
    qf0[jq] = (bf16)((float)qf0[jq] * QSCL);
    qf1[jq] = (bf16)((float)qf1[jq] * QSCL);
  }

  f32x4 o[4] = {};
  float mrow = -1e30f, ell = 0.f;   // ell = per-lane partial (16 s-cols)

  stage(0, t0);

  int cur = 0;
#pragma unroll 1
  for (int t = t0; t < t1; ++t) {
    __syncthreads();   // stage(t) landed everywhere; all waves done with t-1

    if (t + 1 < t1) stage(cur ^ 1, t + 1);

    f32x4 ss[4] = {};
    __builtin_amdgcn_s_setprio(1);
#pragma unroll
    for (int st = 0; st < 4; ++st) {
      bf16x8 ka  = *(const bf16x8*)swz(&Ks[cur][0], st * 16 + c, g * 16);
      bf16x8 kb2 = *(const bf16x8*)swz(&Ks[cur][0], st * 16 + c, 64 + g * 16);
      ss[st] = __builtin_amdgcn_mfma_f32_16x16x32_bf16(ka,  qf0, ss[st], 0, 0, 0);
      ss[st] = __builtin_amdgcn_mfma_f32_16x16x32_bf16(kb2, qf1, ss[st], 0, 0, 0);
    }
    __builtin_amdgcn_s_setprio(0);

    float mloc = -1e30f;
    if (t >= tmaskw) {
#pragma unroll
      for (int st = 0; st < 4; ++st)
#pragma unroll
        for (int r = 0; r < 4; ++r) {
          int ci = t * 64 + st * 16 + g * 4 + r;
          int s = ci2s(ci);
          if (t == 0) s = (ci < 2) ? ci : s;
          float v = (s <= qq) ? ss[st][r] : -1e30f;
          ss[st][r] = v;
          mloc = fmaxf(mloc, v);
        }
    } else {
#pragma unroll
      for (int st = 0; st < 4; ++st)
#pragma unroll
        for (int r = 0; r < 4; ++r) mloc = fmaxf(mloc, ss[st][r]);
    }
    mloc = fmaxf(mloc, __shfl_xor(mloc, 16));
    mloc = fmaxf(mloc, __shfl_xor(mloc, 32));

    // defer-max: rescale only when some row's max grew by >12 (log2 units)
    if (!__all(mloc - mrow <= 12.0f)) {
      float mn = fmaxf(mrow, mloc);
      float al = exp2f(mrow - mn);
      mrow = mn;
      ell *= al;
#pragma unroll
      for (int dc = 0; dc < 4; ++dc)
#pragma unroll
        for (int r = 0; r < 4; ++r) o[dc][r] *= al;
    }

    float rsum = 0.f;
#pragma unroll
    for (int st = 0; st < 4; ++st) {
      float p0 = exp2f(ss[st][0] - mrow);
      float p1 = exp2f(ss[st][1] - mrow);
      float p2 = exp2f(ss[st][2] - mrow);
      float p3 = exp2f(ss[st][3] - mrow);
      rsum += (p0 + p1) + (p2 + p3);
      bf16x4 pk = {(bf16)p0, (bf16)p1, (bf16)p2, (bf16)p3};
      *(bf16x4*)swz(&Plds[w][0], c, st * 32 + g * 8) = pk;
    }
    ell += rsum;       // per-lane partial; cross-lane reduced once at end

    // wave-private P cross-lane round trip (rule #18 fence pair)
    asm volatile("s_waitcnt lgkmcnt(0)" ::: "memory");
    __builtin_amdgcn_sched_barrier(0);

    __builtin_amdgcn_s_setprio(1);
#pragma unroll
    for (int kk = 0; kk < 2; ++kk) {
      bf16x8 pf = *(const bf16x8*)swz(&Plds[w][0], c, kk * 64 + g * 16);
#pragma unroll
      for (int dc = 0; dc < 4; ++dc) {
        bf16x8 vf = *(const bf16x8*)swz(&Vs[cur][0], dc * 16 + c, kk * 64 + g * 16);
        o[dc] = __builtin_amdgcn_mfma_f32_16x16x32_bf16(vf, pf, o[dc], 0, 0, 0);
      }
    }
    __builtin_amdgcn_s_setprio(0);

    cur ^= 1;
  }

  // ---- epilogue: reduce ell across the 4 g-lanes (same q=c row) ----
  float et = ell;
  et += __shfl_xor(et, 16);
  et += __shfl_xor(et, 32);

  if (split) {
    // raw partials: po[slot][row=w*16+c][d], pml[slot][row][{m,l}]
    float* prow = po + ((size_t)slot * 64 + w * 16 + c) * 64;
#pragma unroll
    for (int dc = 0; dc < 4; ++dc)
      *(f32x4*)(prow + dc * 16 + g * 4) = o[dc];
    if (g == 0) {
      float* pm = pml + ((size_t)slot * 64 + w * 16 + c) * 2;
      pm[0] = mrow;
      pm[1] = et;
    }
    return;
  }

  float inv = 1.f / et;
#pragma unroll
  for (int dc = 0; dc < 4; ++dc) {
    bf16x4 ok4 = {(bf16)(o[dc][0] * inv), (bf16)(o[dc][1] * inv),
                  (bf16)(o[dc][2] * inv), (bf16)(o[dc][3] * inv)};
    *(bf16x4*)swz(&Plds[w][0], c, dc * 32 + g * 8) = ok4;
  }
  asm volatile("s_waitcnt lgkmcnt(0)" ::: "memory");
  __builtin_amdgcn_sched_barrier(0);
#pragma unroll
  for (int p = 0; p < 2; ++p) {
    int row = p * 8 + (l >> 3);
    bf16x8 vrow = *(const bf16x8*)swz(&Plds[w][0], row, (l & 7) * 16);
    *(bf16x8*)&att[(size_t)(b * 2048 + qt * 64 + w * 16 + row) * 1024 +
                   h * 64 + (l & 7) * 8] = vrow;
  }
}

// ---------------- merge of split-attn partials ----------------------------
// 512 blocks = 32 bh x 16 qt-slots (qt = 16+qi). Standard (m,l,o) combine.
__global__ __launch_bounds__(256) void k_merge(const float* __restrict__ po,
                                               const float* __restrict__ pml,
                                               bf16* __restrict__ att) {
  int mb = blockIdx.x;
  int bh = mb & 31, qi = mb >> 5;
  int b = bh >> 4, h = bh & 15;
  int t = threadIdx.x;
  int row = t & 63, dg = t >> 6;          // dg 0..3 -> 16 d each
  size_t slot0 = (size_t)(bh * 16 + qi) * 2;
  size_t r0 = (slot0 * 64 + row) * 64, r1 = ((slot0 + 1) * 64 + row) * 64;
  float m0 = pml[(slot0 * 64 + row) * 2],     l0 = pml[(slot0 * 64 + row) * 2 + 1];
  float m1 = pml[((slot0 + 1) * 64 + row) * 2], l1 = pml[((slot0 + 1) * 64 + row) * 2 + 1];
  float m = fmaxf(m0, m1);
  float a0 = exp2f(m0 - m), a1 = exp2f(m1 - m);
  float inv = 1.f / (a0 * l0 + a1 * l1);
  int q = (16 + qi) * 64 + row;
  bf16* dst = att + (size_t)(b * 2048 + q) * 1024 + h * 64 + dg * 16;
#pragma unroll
  for (int jd = 0; jd < 16; jd += 4) {
    f32x4 v0 = *(const f32x4*)&po[r0 + dg * 16 + jd];
    f32x4 v1 = *(const f32x4*)&po[r1 + dg * 16 + jd];
    bf16x4 r;
#pragma unroll
    for (int i = 0; i < 4; ++i)
      r[i] = (bf16)((a0 * v0[i] + a1 * v1[i]) * inv);
    *(bf16x4*)(dst + jd) = r;
  }
}

// ---------------- launcher ----------------
extern "C" void kernel_launch(void* const* d_in, const int* in_sizes, int n_in,
                              void* d_out, int out_size, void* d_ws, size_t ws_size,
                              hipStream_t stream) {
  const float* x  = (const float*)d_in[0];
  const float* Wq = (const float*)d_in[1];
  const float* bq = (const float*)d_in[2];
  const float* Wk = (const float*)d_in[3];
  const float* bk = (const float*)d_in[4];
  const float* Wv = (const float*)d_in[5];
  const float* bv = (const float*)d_in[6];
  const float* Wp = (const float*)d_in[7];
  const float* bp = (const float*)d_in[8];
  float* out = (float*)d_out;

  char* ws = (char*)d_ws;
  const size_t MB = 1024 * 1024;
  bf16*  xb    = (bf16*)(ws);             // 8 MB [4096][1024]; reused as att
  bf16*  wqkvT = (bf16*)(ws + 8 * MB);    // 6 MB [3072][1024]
  bf16*  wpT   = (bf16*)(ws + 14 * MB);   // 2 MB [1024][1024]
  float* bcat  = (float*)(ws + 16 * MB);  // 12 KB
  bf16*  qkv   = (bf16*)(ws + 17 * MB);   // 24 MB [4096][3072]
  bf16*  vcb   = (bf16*)(ws + 41 * MB);   // 5.5 MB [32][64][1408]
  float* po    = (float*)(ws + 56 * MB);  // 16.8 MB [1024 slots][64][64] f32
  float* pml   = (float*)(ws + 74 * MB);  // 0.5 MB  [1024 slots][64][2] f32
  bf16*  att   = xb;                      // alias: xb dead after QKV GEMM

  // 1: all preps (cvt + 4x W^T + bias concat)
  k_prep<<<4108, 256, 0, stream>>>(x, Wq, Wk, Wv, Wp, bq, bk, bv,
                                   xb, wqkvT, wpT, bcat);
  // 2: QKV GEMM [4096,1024]x[1024,3072], 128x128 tiles (768 blocks, 3/CU)
  k_gemm_bt<bf16, 128, 128, 32><<<dim3(32, 24), 256, 0, stream>>>(
      xb, wqkvT, bcat, qkv, 1024, 3072);
  // 3: V gather/transpose only (K read directly from qkv by attn)
  k_compact<<<704, 256, 0, stream>>>(qkv, vcb);
  // 4: attention, chain-split (1536 blocks; qt>=16 halved across 2 blocks)
  k_attn<<<1536, 256, 0, stream>>>(qkv, vcb, att, po, pml);
  // 4b: merge split partials into att rows 1024..2047
  k_merge<<<512, 256, 0, stream>>>(po, pml, att);
  // 5: output projection, 64x128 tiles (512 blocks = 2/CU overlap), BK=64
  k_gemm_bt<float, 64, 128, 64><<<dim3(64, 8), 256, 0, stream>>>(
      att, wpT, bp, out, 1024, 1024);
}

// Round 18
// 102.838 us; speedup vs baseline: 1.0898x; 1.0898x over previous
//
#include <hip/hip_runtime.h>

#define AS_GLOBAL __attribute__((address_space(1)))
#define AS_LDS    __attribute__((address_space(3)))

typedef __bf16 bf16;
typedef __bf16 bf16x4 __attribute__((ext_vector_type(4)));
typedef __bf16 bf16x8 __attribute__((ext_vector_type(8)));
typedef float  f32x4  __attribute__((ext_vector_type(4)));
typedef unsigned short u16x8 __attribute__((ext_vector_type(8)));

__device__ __forceinline__ void gload16(const void* g, void* l) {
  __builtin_amdgcn_global_load_lds((const AS_GLOBAL unsigned int*)g,
                                   (AS_LDS unsigned int*)l, 16, 0, 0);
}

// swizzled LDS address for a [R][128B] row-major tile:
// stored_byte = row*128 + (bytecol ^ ((row&7)<<4))
__device__ __forceinline__ void* swz(void* base, int row, int bytecol) {
  return (char*)base + row * 128 + (bytecol ^ ((row & 7) << 4));
}

// compacted-column helpers: kept columns are s with !(s%3==1 && s>=4).
__device__ __forceinline__ int keptcnt(int X) { return X - ((X - 2) < 0 ? 0 : (X - 2) / 3); }
__device__ __forceinline__ int ci2s(int ci) {
  return 3 * ((ci - 2) >> 1) + 2 + ((ci - 2) & 1);
}
__device__ __forceinline__ int ci2s_full(int ci) {
  return ci < 2 ? ci : ci2s(ci);
}

// ---------------- fused prep: x->bf16 | 4x W^T | bias concat --------------
__global__ __launch_bounds__(256) void k_prep(const float* __restrict__ x,
                                              const float* __restrict__ Wq,
                                              const float* __restrict__ Wk,
                                              const float* __restrict__ Wv,
                                              const float* __restrict__ Wp,
                                              const float* __restrict__ bq,
                                              const float* __restrict__ bk,
                                              const float* __restrict__ bv,
                                              bf16* __restrict__ xb,
                                              bf16* __restrict__ wqkvT,
                                              bf16* __restrict__ wpT,
                                              float* __restrict__ bc) {
  int blk = blockIdx.x;
  if (blk < 2048) {
    int i = blk * 256 + threadIdx.x;
    const float4* p = (const float4*)(x + (size_t)i * 8);
    float4 a = p[0], b = p[1];
    bf16x8 v;
    v[0] = (bf16)a.x; v[1] = (bf16)a.y; v[2] = (bf16)a.z; v[3] = (bf16)a.w;
    v[4] = (bf16)b.x; v[5] = (bf16)b.y; v[6] = (bf16)b.z; v[7] = (bf16)b.w;
    *(bf16x8*)(xb + (size_t)i * 8) = v;
  } else if (blk < 4096) {
    int wblk = blk - 2048;
    int sel = wblk >> 9;
    const float* W = (sel == 0) ? Wq : (sel == 1) ? Wk : (sel == 2) ? Wv : Wp;
    bf16* dst = (sel < 3) ? (wqkvT + (size_t)sel * 1024 * 1024) : wpT;
    int lin = (wblk & 511) * 256 + threadIdx.x;
    int n = lin & 1023, kc = lin >> 10;
    bf16x8 v;
#pragma unroll
    for (int j = 0; j < 8; ++j) v[j] = (bf16)W[(size_t)(kc * 8 + j) * 1024 + n];
    *(bf16x8*)&dst[(size_t)n * 1024 + kc * 8] = v;
  } else {
    int i = (blk - 4096) * 256 + threadIdx.x;   // 0..3071
    bc[i] = (i < 1024) ? bq[i] : (i < 2048 ? bk[i - 1024] : bv[i - 2048]);
  }
}

// ---------------- V compact: gather + transpose -> Vc[bh][64][1408] -------
__global__ __launch_bounds__(256) void k_compact(const bf16* __restrict__ qkv,
                                                 bf16* __restrict__ vc) {
  __shared__ unsigned L[32 * 65];
  int blk = blockIdx.x;                 // 32 bh * 22 cichunks = 704
  int tid = threadIdx.x;
  int bh = blk / 22, cc = blk % 22;
  int b = bh >> 4, h = bh & 15;
  int ci0 = cc * 64;
  int p = tid >> 3, d0 = (tid & 7) * 8;
  int s0 = ci2s_full(ci0 + 2 * p), s1 = ci2s_full(ci0 + 2 * p + 1);
  u16x8 e = {}, od = {};
  if (s0 < 2048)
    e = *(const u16x8*)&qkv[(size_t)(b * 2048 + s0) * 3072 + 2048 + h * 64 + d0];
  if (s1 < 2048)
    od = *(const u16x8*)&qkv[(size_t)(b * 2048 + s1) * 3072 + 2048 + h * 64 + d0];
#pragma unroll
  for (int k2 = 0; k2 < 8; ++k2)
    L[p * 65 + d0 + k2] = (unsigned)e[k2] | ((unsigned)od[k2] << 16);
  __syncthreads();
#pragma unroll
  for (int it = 0; it < 2; ++it) {
    int d = it * 32 + (tid >> 3), jg = tid & 7;
    unsigned q4[4];
#pragma unroll
    for (int jj = 0; jj < 4; ++jj) q4[jj] = L[(jg * 4 + jj) * 65 + d];
    *(uint4*)&vc[((size_t)bh * 64 + d) * 1408 + ci0 + jg * 8] = *(uint4*)q4;
  }
}

// ---------------- dbuf GEMM, templated tile TMxTN, BK ---------------------
// 4 waves as 2x2; wave tile (TM/2)x(TN/2). Granule XOR-swizzle both sides.
// QKV: <bf16,128,128,32> (768 blocks, 3/CU). Out-proj: <float,64,128,64>
// (512 blocks, 2/CU: doubles per-CU overlap at 1-block-exposed latency).
template <typename OutT, int TM, int TN, int BK>
__global__ __launch_bounds__(256) void k_gemm_bt(const bf16* __restrict__ A,
                                                 const bf16* __restrict__ Bt,
                                                 const float* __restrict__ bias,
                                                 OutT* __restrict__ C,
                                                 int K, int N) {
  constexpr int GR = BK / 8;            // 16B granules per LDS row
  constexpr int MF = TM / 32, NF = TN / 32, KF = BK / 32;
  __shared__ bf16 As[2][TM * BK];
  __shared__ bf16 Bs[2][TN * BK];
  const int tid = threadIdx.x;
  const int w = tid >> 6, l = tid & 63, g = l >> 4, c = l & 15;
  const int wr = w >> 1, wc = w & 1;
  int lin = blockIdx.y * gridDim.x + blockIdx.x;
  int chunk = (gridDim.x * gridDim.y) >> 3;
  int nl = (lin & 7) * chunk + (lin >> 3);
  const int row0 = (nl % gridDim.x) * TM, col0 = (nl / gridDim.x) * TN;
  f32x4 acc[MF][NF] = {};

  auto swzj = [&](int j, int r) {
    if constexpr (BK == 32) return j ^ ((r >> 1) & 3);
    else                    return j ^ (r & 7);
  };

  auto stage = [&](int buf, int k0) {
#pragma unroll
    for (int it = 0; it < (TM * GR) / 256; ++it) {
      int idx = it * 256 + tid;
      int r = idx / GR, j = idx % GR;
      gload16(A + (size_t)(row0 + r) * K + k0 + swzj(j, r) * 8, &As[buf][idx * 8]);
    }
#pragma unroll
    for (int it = 0; it < (TN * GR) / 256; ++it) {
      int idx = it * 256 + tid;
      int r = idx / GR, j = idx % GR;
      gload16(Bt + (size_t)(col0 + r) * K + k0 + swzj(j, r) * 8, &Bs[buf][idx * 8]);
    }
  };

  stage(0, 0);
  int cur = 0;
#pragma unroll 1
  for (int k0 = 0; k0 < K; k0 += BK) {
    __syncthreads();   // drains vmcnt (stage(k0) landed) + full memory fence

    if (k0 + BK < K) stage(cur ^ 1, k0 + BK);

    bf16x8 af[MF][KF], bfr[NF][KF];
#pragma unroll
    for (int m = 0; m < MF; ++m) {
      int row = wr * (TM / 2) + m * 16 + c;
#pragma unroll
      for (int kk = 0; kk < KF; ++kk)
        af[m][kk] = *(const bf16x8*)&As[cur][row * BK + swzj(kk * 4 + g, row) * 8];
    }
#pragma unroll
    for (int n = 0; n < NF; ++n) {
      int row = wc * (TN / 2) + n * 16 + c;
#pragma unroll
      for (int kk = 0; kk < KF; ++kk)
        bfr[n][kk] = *(const bf16x8*)&Bs[cur][row * BK + swzj(kk * 4 + g, row) * 8];
    }
#pragma unroll
    for (int m = 0; m < MF; ++m)
#pragma unroll
      for (int n = 0; n < NF; ++n)
#pragma unroll
        for (int kk = 0; kk < KF; ++kk)
          acc[m][n] = __builtin_amdgcn_mfma_f32_16x16x32_bf16(af[m][kk], bfr[n][kk],
                                                              acc[m][n], 0, 0, 0);
    cur ^= 1;
  }

#pragma unroll
  for (int m = 0; m < MF; ++m) {
    int row = row0 + wr * (TM / 2) + m * 16 + g * 4;
#pragma unroll
    for (int n = 0; n < NF; ++n) {
      int col = col0 + wc * (TN / 2) + n * 16 + c;
      float bv = bias[col];
#pragma unroll
      for (int r = 0; r < 4; ++r) {
        float v = acc[m][n][r] + bv;
        C[(size_t)(row + r) * N + col] = (OutT)v;
      }
    }
  }
}

// ---------------- flash attention v12: R16-proven config ------------------
// 1024 blocks, 64 q-rows, 4 waves, 40KB LDS, 4 blocks/CU. Swapped QK^T,
// lane-local softmax in exp2 domain, defer-max, deferred-ell, T5 setprio,
// K direct-gathered from qkv, compacted V. Pure __syncthreads sync.
__global__ __launch_bounds__(256, 4) void k_attn(const bf16* __restrict__ qkv,
                                                 const bf16* __restrict__ vc,
                                                 bf16* __restrict__ att) {
  const int idx = blockIdx.x;
  const int slot = idx >> 8, j = idx & 255;
  const int r8 = j >> 5, bh = j & 31;
  const int b = bh >> 4, h = bh & 15;
  int qt;
  switch (slot) {
    case 0: qt = r8;       break;
    case 1: qt = 31 - r8;  break;
    case 2: qt = r8 + 8;   break;
    default: qt = 23 - r8; break;
  }

  const int tid = threadIdx.x;
  const int w = tid >> 6, l = tid & 63, g = l >> 4, c = l & 15;
  const int qw0 = qt * 64 + w * 16;
  const int qq = qw0 + c;

  const int nt = (keptcnt(qt * 64 + 64) + 63) >> 6;
  const int tmaskw = keptcnt(qw0 + 1) >> 6;

  __shared__ bf16 Ks[2][64 * 64];
  __shared__ bf16 Vs[2][64 * 64];
  __shared__ bf16 Plds[4][16 * 64];

  const bf16* vgc = vc + (size_t)bh * 64 * 1408;

  auto stage = [&](int buf, int t) {
    int s0 = t * 64;
#pragma unroll
    for (int it = 0; it < 2; ++it) {
      int ch = it * 256 + tid;
      int rr = ch >> 3, jj = (ch & 7) ^ (rr & 7);
      int s = ci2s_full(s0 + rr);
      s = (s < 2048) ? s : 0;             // pad: load row 0; masked by s<=qq
      gload16(qkv + (size_t)(b * 2048 + s) * 3072 + 1024 + h * 64 + jj * 8,
              &Ks[buf][ch * 8]);
      gload16(vgc + (size_t)rr * 1408 + s0 + jj * 8, &Vs[buf][ch * 8]);
    }
  };

  // Q B-frag, pre-scaled by 0.125*log2e -> S in log2 domain
  const float QSCL = 0.125f * 1.44269504f;
  const bf16* qb = qkv + (size_t)(b * 2048 + qq) * 3072 + h * 64 + g * 8;
  bf16x8 qf0 = *(const bf16x8*)qb;
  bf16x8 qf1 = *(const bf16x8*)(qb + 32);
#pragma unroll
  for (int jq = 0; jq < 8; ++jq) {
    qf0[jq] = (bf16)((float)qf0[jq] * QSCL);
    qf1[jq] = (bf16)((float)qf1[jq] * QSCL);
  }

  f32x4 o[4] = {};
  float mrow = -1e30f, ell = 0.f;   // ell = per-lane partial (16 s-cols)

  stage(0, 0);

  int cur = 0;
#pragma unroll 1
  for (int t = 0; t < nt; ++t) {
    __syncthreads();   // stage(t) landed everywhere; all waves done with t-1

    if (t + 1 < nt) stage(cur ^ 1, t + 1);

    f32x4 ss[4] = {};
    __builtin_amdgcn_s_setprio(1);
#pragma unroll
    for (int st = 0; st < 4; ++st) {
      bf16x8 ka  = *(const bf16x8*)swz(&Ks[cur][0], st * 16 + c, g * 16);
      bf16x8 kb2 = *(const bf16x8*)swz(&Ks[cur][0], st * 16 + c, 64 + g * 16);
      ss[st] = __builtin_amdgcn_mfma_f32_16x16x32_bf16(ka,  qf0, ss[st], 0, 0, 0);
      ss[st] = __builtin_amdgcn_mfma_f32_16x16x32_bf16(kb2, qf1, ss[st], 0, 0, 0);
    }
    __builtin_amdgcn_s_setprio(0);

    float mloc = -1e30f;
    if (t >= tmaskw) {
#pragma unroll
      for (int st = 0; st < 4; ++st)
#pragma unroll
        for (int r = 0; r < 4; ++r) {
          int ci = t * 64 + st * 16 + g * 4 + r;
          int s = ci2s(ci);
          if (t == 0) s = (ci < 2) ? ci : s;
          float v = (s <= qq) ? ss[st][r] : -1e30f;
          ss[st][r] = v;
          mloc = fmaxf(mloc, v);
        }
    } else {
#pragma unroll
      for (int st = 0; st < 4; ++st)
#pragma unroll
        for (int r = 0; r < 4; ++r) mloc = fmaxf(mloc, ss[st][r]);
    }
    mloc = fmaxf(mloc, __shfl_xor(mloc, 16));
    mloc = fmaxf(mloc, __shfl_xor(mloc, 32));

    // defer-max: rescale only when some row's max grew by >12 (log2 units)
    if (!__all(mloc - mrow <= 12.0f)) {
      float mn = fmaxf(mrow, mloc);
      float al = exp2f(mrow - mn);
      mrow = mn;
      ell *= al;
#pragma unroll
      for (int dc = 0; dc < 4; ++dc)
#pragma unroll
        for (int r = 0; r < 4; ++r) o[dc][r] *= al;
    }

    float rsum = 0.f;
#pragma unroll
    for (int st = 0; st < 4; ++st) {
      float p0 = exp2f(ss[st][0] - mrow);
      float p1 = exp2f(ss[st][1] - mrow);
      float p2 = exp2f(ss[st][2] - mrow);
      float p3 = exp2f(ss[st][3] - mrow);
      rsum += (p0 + p1) + (p2 + p3);
      bf16x4 pk = {(bf16)p0, (bf16)p1, (bf16)p2, (bf16)p3};
      *(bf16x4*)swz(&Plds[w][0], c, st * 32 + g * 8) = pk;
    }
    ell += rsum;       // per-lane partial; cross-lane reduced once at end

    // wave-private P cross-lane round trip (rule #18 fence pair)
    asm volatile("s_waitcnt lgkmcnt(0)" ::: "memory");
    __builtin_amdgcn_sched_barrier(0);

    __builtin_amdgcn_s_setprio(1);
#pragma unroll
    for (int kk = 0; kk < 2; ++kk) {
      bf16x8 pf = *(const bf16x8*)swz(&Plds[w][0], c, kk * 64 + g * 16);
#pragma unroll
      for (int dc = 0; dc < 4; ++dc) {
        bf16x8 vf = *(const bf16x8*)swz(&Vs[cur][0], dc * 16 + c, kk * 64 + g * 16);
        o[dc] = __builtin_amdgcn_mfma_f32_16x16x32_bf16(vf, pf, o[dc], 0, 0, 0);
      }
    }
    __builtin_amdgcn_s_setprio(0);

    cur ^= 1;
  }

  // ---- epilogue: reduce ell across the 4 g-lanes (same q=c row) ----
  float et = ell;
  et += __shfl_xor(et, 16);
  et += __shfl_xor(et, 32);
  float inv = 1.f / et;
#pragma unroll
  for (int dc = 0; dc < 4; ++dc) {
    bf16x4 ok4 = {(bf16)(o[dc][0] * inv), (bf16)(o[dc][1] * inv),
                  (bf16)(o[dc][2] * inv), (bf16)(o[dc][3] * inv)};
    *(bf16x4*)swz(&Plds[w][0], c, dc * 32 + g * 8) = ok4;
  }
  asm volatile("s_waitcnt lgkmcnt(0)" ::: "memory");
  __builtin_amdgcn_sched_barrier(0);
#pragma unroll
  for (int p = 0; p < 2; ++p) {
    int row = p * 8 + (l >> 3);
    bf16x8 vrow = *(const bf16x8*)swz(&Plds[w][0], row, (l & 7) * 16);
    *(bf16x8*)&att[(size_t)(b * 2048 + qt * 64 + w * 16 + row) * 1024 +
                   h * 64 + (l & 7) * 8] = vrow;
  }
}

// ---------------- launcher ----------------
extern "C" void kernel_launch(void* const* d_in, const int* in_sizes, int n_in,
                              void* d_out, int out_size, void* d_ws, size_t ws_size,
                              hipStream_t stream) {
  const float* x  = (const float*)d_in[0];
  const float* Wq = (const float*)d_in[1];
  const float* bq = (const float*)d_in[2];
  const float* Wk = (const float*)d_in[3];
  const float* bk = (const float*)d_in[4];
  const float* Wv = (const float*)d_in[5];
  const float* bv = (const float*)d_in[6];
  const float* Wp = (const float*)d_in[7];
  const float* bp = (const float*)d_in[8];
  float* out = (float*)d_out;

  char* ws = (char*)d_ws;
  const size_t MB = 1024 * 1024;
  bf16*  xb    = (bf16*)(ws);             // 8 MB [4096][1024]; reused as att
  bf16*  wqkvT = (bf16*)(ws + 8 * MB);    // 6 MB [3072][1024]
  bf16*  wpT   = (bf16*)(ws + 14 * MB);   // 2 MB [1024][1024]
  float* bcat  = (float*)(ws + 16 * MB);  // 12 KB
  bf16*  qkv   = (bf16*)(ws + 17 * MB);   // 24 MB [4096][3072]
  bf16*  vcb   = (bf16*)(ws + 41 * MB);   // 5.5 MB [32][64][1408]
  bf16*  att   = xb;                      // alias: xb dead after QKV GEMM

  // 1: all preps (cvt + 4x W^T + bias concat)
  k_prep<<<4108, 256, 0, stream>>>(x, Wq, Wk, Wv, Wp, bq, bk, bv,
                                   xb, wqkvT, wpT, bcat);
  // 2: QKV GEMM [4096,1024]x[1024,3072], 128x128 tiles (768 blocks, 3/CU)
  k_gemm_bt<bf16, 128, 128, 32><<<dim3(32, 24), 256, 0, stream>>>(
      xb, wqkvT, bcat, qkv, 1024, 3072);
  // 3: V gather/transpose only (K read directly from qkv by attn)
  k_compact<<<704, 256, 0, stream>>>(qkv, vcb);
  // 4: attention (R16-proven: R12 geometry + exp2/defer-max/setprio)
  k_attn<<<1024, 256, 0, stream>>>(qkv, vcb, att);
  // 5: output projection, 64x128 tiles (512 blocks = 2/CU overlap), BK=64
  k_gemm_bt<float, 64, 128, 64><<<dim3(64, 8), 256, 0, stream>>>(
      att, wpT, bp, out, 1024, 1024);
}